// Round 3
// baseline (1463.141 us; speedup 1.0000x reference)
//
#include <hip/hip_runtime.h>

typedef float f2v __attribute__((ext_vector_type(2)));
typedef unsigned short u16x8 __attribute__((ext_vector_type(8)));

// ---------- bf16 helpers (RNE) ----------
__device__ __forceinline__ unsigned short f2bf(float f) {
    unsigned u = __float_as_uint(f);
    unsigned r = (u + 0x7FFFu + ((u >> 16) & 1u)) >> 16;
    return (unsigned short)r;
}
__device__ __forceinline__ float bf2f(unsigned short h) {
    return __uint_as_float(((unsigned)h) << 16);
}

// ---------- tiled layout: tile = 8 wide x 4 tall = 32 bf16 texels = 64 B ----------
__device__ __forceinline__ int tiled_off(int W, int x, int y) {
    // element offset (ushort units)
    return (((y >> 2) * (W >> 3) + (x >> 3)) << 5) + ((y & 3) << 3) + (x & 7);
}

template <bool NT>
__global__ __launch_bounds__(256) void convert_tiled(const float* __restrict__ src,
                                                     unsigned short* __restrict__ dst,
                                                     int W, int total /* (W>>3)*H */) {
    int t = blockIdx.x * blockDim.x + threadIdx.x;
    if (t >= total) return;
    int wp = W >> 3;
    int y = t / wp;
    int xg = (t - y * wp) << 3;
    const float4* s = (const float4*)(src + (size_t)y * W + xg);
    float4 a = s[0], b = s[1];
    u16x8 r;
    r[0] = f2bf(a.x); r[1] = f2bf(a.y); r[2] = f2bf(a.z); r[3] = f2bf(a.w);
    r[4] = f2bf(b.x); r[5] = f2bf(b.y); r[6] = f2bf(b.z); r[7] = f2bf(b.w);
    u16x8* d = (u16x8*)(dst + tiled_off(W, xg, y));
    if (NT) __builtin_nontemporal_store(r, d);
    else    *d = r;
}

// ---------- bilinear sample from tiled bf16 ----------
// NT: use non-temporal (evict-first) loads so this layer's miss stream
// doesn't thrash the 4 MB per-XCD L2 that the small layers live in.
template <int W, int H, bool NT>
__device__ __forceinline__ float sample_layer_t(const unsigned short* __restrict__ t,
                                                float gx, float gy) {
    float ix = ((gx + 1.0f) * (float)W - 1.0f) * 0.5f;
    float iy = ((gy + 1.0f) * (float)H - 1.0f) * 0.5f;
    float x0f = floorf(ix), y0f = floorf(iy);
    float wx1 = ix - x0f, wy1 = iy - y0f;
    float wx0 = 1.0f - wx1, wy0 = 1.0f - wy1;
    int x0 = (int)x0f, y0 = (int)y0f;
    int x1 = x0 + 1, y1 = y0 + 1;
    bool vx0 = (unsigned)x0 < (unsigned)W, vx1 = (unsigned)x1 < (unsigned)W;
    bool vy0 = (unsigned)y0 < (unsigned)H, vy1 = (unsigned)y1 < (unsigned)H;
    int cx0 = min(max(x0, 0), W - 1), cx1 = min(max(x1, 0), W - 1);
    int cy0 = min(max(y0, 0), H - 1), cy1 = min(max(y1, 0), H - 1);
    unsigned short r00, r10, r01, r11;
    if (NT) {
        r00 = __builtin_nontemporal_load(t + tiled_off(W, cx0, cy0));
        r10 = __builtin_nontemporal_load(t + tiled_off(W, cx1, cy0));
        r01 = __builtin_nontemporal_load(t + tiled_off(W, cx0, cy1));
        r11 = __builtin_nontemporal_load(t + tiled_off(W, cx1, cy1));
    } else {
        r00 = t[tiled_off(W, cx0, cy0)];
        r10 = t[tiled_off(W, cx1, cy0)];
        r01 = t[tiled_off(W, cx0, cy1)];
        r11 = t[tiled_off(W, cx1, cy1)];
    }
    float v00 = bf2f(r00); v00 = (vx0 & vy0) ? v00 : 0.0f;
    float v10 = bf2f(r10); v10 = (vx1 & vy0) ? v10 : 0.0f;
    float v01 = bf2f(r01); v01 = (vx0 & vy1) ? v01 : 0.0f;
    float v11 = bf2f(r11); v11 = (vx1 & vy1) ? v11 : 0.0f;
    return v00 * (wx0 * wy0) + v10 * (wx1 * wy0) + v01 * (wx0 * wy1) + v11 * (wx1 * wy1);
}

__global__ __launch_bounds__(256) void texture_sample_tiled(
        const f2v* __restrict__ x,
        const unsigned short* __restrict__ l1,
        const unsigned short* __restrict__ l2,
        const unsigned short* __restrict__ l3,
        const unsigned short* __restrict__ l4,
        float* __restrict__ out, int n) {
    int i = blockIdx.x * blockDim.x + threadIdx.x;
    if (i >= n) return;
    f2v g = __builtin_nontemporal_load(x + i);
    float gx = g.x * 2.0f - 1.0f;
    float gy = g.y * 2.0f - 1.0f;
    float acc;
    acc  = sample_layer_t<4096, 4096, true >(l1, gx, gy);  // 32 MB: stream, don't cache
    acc += sample_layer_t<2048, 2048, false>(l2, gx, gy);  // 8 MB: partially L2-resident
    acc += sample_layer_t<1024, 1024, false>(l3, gx, gy);  // 2 MB: L2-resident
    acc += sample_layer_t< 512,  512, false>(l4, gx, gy);  // 0.5 MB: L2-resident
    __builtin_nontemporal_store(acc, out + i);
}

// ---------- fallback: direct fp32 path (used only if ws too small) ----------
__device__ __forceinline__ float fetch_tap(const float* __restrict__ t, int W, int H, int x, int y) {
    bool valid = ((unsigned)x < (unsigned)W) & ((unsigned)y < (unsigned)H);
    int xc = min(max(x, 0), W - 1);
    int yc = min(max(y, 0), H - 1);
    float v = t[(size_t)yc * (size_t)W + (size_t)xc];
    return valid ? v : 0.0f;
}
__device__ __forceinline__ float sample_layer(const float* __restrict__ t, int W, int H,
                                              float gx, float gy) {
    float ix = ((gx + 1.0f) * (float)W - 1.0f) * 0.5f;
    float iy = ((gy + 1.0f) * (float)H - 1.0f) * 0.5f;
    float x0f = floorf(ix), y0f = floorf(iy);
    float wx1 = ix - x0f, wy1 = iy - y0f;
    float wx0 = 1.0f - wx1, wy0 = 1.0f - wy1;
    int x0 = (int)x0f, y0 = (int)y0f;
    float v00 = fetch_tap(t, W, H, x0,     y0);
    float v10 = fetch_tap(t, W, H, x0 + 1, y0);
    float v01 = fetch_tap(t, W, H, x0,     y0 + 1);
    float v11 = fetch_tap(t, W, H, x0 + 1, y0 + 1);
    return (v00 * wx0 + v10 * wx1) * wy0 + (v01 * wx0 + v11 * wx1) * wy1;
}
__global__ __launch_bounds__(256) void texture_sample_direct(
        const f2v* __restrict__ x,
        const float* __restrict__ l1, const float* __restrict__ l2,
        const float* __restrict__ l3, const float* __restrict__ l4,
        float* __restrict__ out, int n) {
    int i = blockIdx.x * blockDim.x + threadIdx.x;
    if (i >= n) return;
    f2v g = __builtin_nontemporal_load(x + i);
    float gx = g.x * 2.0f - 1.0f;
    float gy = g.y * 2.0f - 1.0f;
    float acc;
    acc  = sample_layer(l1, 4096, 4096, gx, gy);
    acc += sample_layer(l2, 2048, 2048, gx, gy);
    acc += sample_layer(l3, 1024, 1024, gx, gy);
    acc += sample_layer(l4,  512,  512, gx, gy);
    __builtin_nontemporal_store(acc, out + i);
}

extern "C" void kernel_launch(void* const* d_in, const int* in_sizes, int n_in,
                              void* d_out, int out_size, void* d_ws, size_t ws_size,
                              hipStream_t stream) {
    const f2v*   x  = (const f2v*)d_in[0];
    const float* l1 = (const float*)d_in[1];
    const float* l2 = (const float*)d_in[2];
    const float* l3 = (const float*)d_in[3];
    const float* l4 = (const float*)d_in[4];
    float* out = (float*)d_out;
    int n = out_size;                       // 4096*4096
    int block = 256;
    int grid = (n + block - 1) / block;

    // ws layout: l1t 32MB | l2t 8MB | l3t 2MB | l4t 0.5MB
    const size_t OFF1 = 0;
    const size_t OFF2 = (size_t)4096 * 4096 * 2;            // 32 MB
    const size_t OFF3 = OFF2 + (size_t)2048 * 2048 * 2;     // +8 MB
    const size_t OFF4 = OFF3 + (size_t)1024 * 1024 * 2;     // +2 MB
    const size_t NEED = OFF4 + (size_t)512 * 512 * 2;       // 42.5 MB total

    if (ws_size >= NEED) {
        unsigned short* t1 = (unsigned short*)((char*)d_ws + OFF1);
        unsigned short* t2 = (unsigned short*)((char*)d_ws + OFF2);
        unsigned short* t3 = (unsigned short*)((char*)d_ws + OFF3);
        unsigned short* t4 = (unsigned short*)((char*)d_ws + OFF4);

        int g1 = (4096 / 8) * 4096, g2 = (2048 / 8) * 2048;
        int g3 = (1024 / 8) * 1024, g4 = (512 / 8) * 512;
        // layer1 conversion writes 32 MB nobody should cache; keep it out of L2
        convert_tiled<true ><<<(g1 + 255) / 256, 256, 0, stream>>>(l1, t1, 4096, g1);
        convert_tiled<false><<<(g2 + 255) / 256, 256, 0, stream>>>(l2, t2, 2048, g2);
        convert_tiled<false><<<(g3 + 255) / 256, 256, 0, stream>>>(l3, t3, 1024, g3);
        convert_tiled<false><<<(g4 + 255) / 256, 256, 0, stream>>>(l4, t4,  512, g4);

        texture_sample_tiled<<<grid, block, 0, stream>>>(x, t1, t2, t3, t4, out, n);
    } else {
        texture_sample_direct<<<grid, block, 0, stream>>>(x, l1, l2, l3, l4, out, n);
    }
}

// Round 4
// 1106.775 us; speedup vs baseline: 1.3220x; 1.3220x over previous
//
#include <hip/hip_runtime.h>

typedef float f2v __attribute__((ext_vector_type(2)));

// ---------- monotone float<->uint key for atomic min/max ----------
__device__ __forceinline__ unsigned fkey(float f) {
    unsigned u = __float_as_uint(f);
    return (u & 0x80000000u) ? ~u : (u | 0x80000000u);
}
__device__ __forceinline__ float funkey(unsigned k) {
    unsigned u = (k & 0x80000000u) ? (k & 0x7FFFFFFFu) : ~k;
    return __uint_as_float(u);
}

__global__ void init_mm(unsigned* mm) {
    int t = threadIdx.x;
    if (t < 4) { mm[2 * t] = 0xFFFFFFFFu; mm[2 * t + 1] = 0u; }
}

// grid-stride min/max over n4 float4's -> mm[0]=minkey, mm[1]=maxkey
__global__ __launch_bounds__(256) void minmax_kernel(const float4* __restrict__ src,
                                                     int n4, unsigned* mm) {
    unsigned kmin = 0xFFFFFFFFu, kmax = 0u;
    int stride = gridDim.x * blockDim.x;
    for (int i = blockIdx.x * blockDim.x + threadIdx.x; i < n4; i += stride) {
        float4 v = src[i];
        unsigned a = fkey(v.x), b = fkey(v.y), c = fkey(v.z), d = fkey(v.w);
        kmin = min(min(kmin, a), min(b, min(c, d)));
        kmax = max(max(kmax, a), max(b, max(c, d)));
    }
    for (int off = 32; off > 0; off >>= 1) {
        kmin = min(kmin, (unsigned)__shfl_xor((int)kmin, off, 64));
        kmax = max(kmax, (unsigned)__shfl_xor((int)kmax, off, 64));
    }
    if ((threadIdx.x & 63) == 0) {
        atomicMin(&mm[0], kmin);
        atomicMax(&mm[1], kmax);
    }
}

// per-layer {vmin, step} from min/max keys
__global__ void finalize_sc(const unsigned* mm, float2* sc) {
    int l = threadIdx.x;
    if (l < 4) {
        float vmin = funkey(mm[2 * l]);
        float vmax = funkey(mm[2 * l + 1]);
        float step = (vmax - vmin) * (1.0f / 255.0f);
        if (!(step > 0.0f)) step = 1.0f;
        sc[l] = make_float2(vmin, step);
    }
}

// ---------- tiled int8 layout: tile = 8x8 texels = 64 B ----------
__device__ __forceinline__ int tiled_off8(int W, int x, int y) {
    return (((y >> 3) * (W >> 3) + (x >> 3)) << 6) + ((y & 7) << 3) + (x & 7);
}

// one thread per 8x8 tile
__global__ __launch_bounds__(256) void convert_tiled_u8(const float* __restrict__ src,
                                                        unsigned char* __restrict__ dst,
                                                        int W, int tilesWShift, int totalTiles,
                                                        const float2* __restrict__ sc, int slot) {
    int tid = blockIdx.x * blockDim.x + threadIdx.x;
    if (tid >= totalTiles) return;
    float2 s = sc[slot];
    float inv = 1.0f / s.y;
    int tilesW = 1 << tilesWShift;
    int tY = tid >> tilesWShift;
    int tX = tid & (tilesW - 1);
    uint2* d = (uint2*)(dst + ((size_t)tid << 6));
#pragma unroll
    for (int r = 0; r < 8; ++r) {
        const float4* s4 = (const float4*)(src + (size_t)(tY * 8 + r) * W + tX * 8);
        float4 a = s4[0], b = s4[1];
        float va[8] = {a.x, a.y, a.z, a.w, b.x, b.y, b.z, b.w};
        unsigned u0 = 0, u1 = 0;
#pragma unroll
        for (int k = 0; k < 4; ++k) {
            int q = (int)rintf((va[k] - s.x) * inv);
            q = min(max(q, 0), 255);
            u0 |= ((unsigned)q) << (8 * k);
        }
#pragma unroll
        for (int k = 0; k < 4; ++k) {
            int q = (int)rintf((va[4 + k] - s.x) * inv);
            q = min(max(q, 0), 255);
            u1 |= ((unsigned)q) << (8 * k);
        }
        d[r] = make_uint2(u0, u1);
    }
}

// ---------- bilinear sample from tiled int8 ----------
template <int W, int H>
__device__ __forceinline__ float sample_layer_u8(const unsigned char* __restrict__ t,
                                                 float vmin, float step,
                                                 float gx, float gy) {
    float ix = ((gx + 1.0f) * (float)W - 1.0f) * 0.5f;
    float iy = ((gy + 1.0f) * (float)H - 1.0f) * 0.5f;
    float x0f = floorf(ix), y0f = floorf(iy);
    float wx1 = ix - x0f, wy1 = iy - y0f;
    float wx0 = 1.0f - wx1, wy0 = 1.0f - wy1;
    int x0 = (int)x0f, y0 = (int)y0f;
    int x1 = x0 + 1, y1 = y0 + 1;
    bool vx0 = (unsigned)x0 < (unsigned)W, vx1 = (unsigned)x1 < (unsigned)W;
    bool vy0 = (unsigned)y0 < (unsigned)H, vy1 = (unsigned)y1 < (unsigned)H;
    int cx0 = min(max(x0, 0), W - 1), cx1 = min(max(x1, 0), W - 1);
    int cy0 = min(max(y0, 0), H - 1), cy1 = min(max(y1, 0), H - 1);
    float q00 = (float)t[tiled_off8(W, cx0, cy0)];
    float q10 = (float)t[tiled_off8(W, cx1, cy0)];
    float q01 = (float)t[tiled_off8(W, cx0, cy1)];
    float q11 = (float)t[tiled_off8(W, cx1, cy1)];
    float v00 = fmaf(q00, step, vmin); v00 = (vx0 & vy0) ? v00 : 0.0f;
    float v10 = fmaf(q10, step, vmin); v10 = (vx1 & vy0) ? v10 : 0.0f;
    float v01 = fmaf(q01, step, vmin); v01 = (vx0 & vy1) ? v01 : 0.0f;
    float v11 = fmaf(q11, step, vmin); v11 = (vx1 & vy1) ? v11 : 0.0f;
    return v00 * (wx0 * wy0) + v10 * (wx1 * wy0) + v01 * (wx0 * wy1) + v11 * (wx1 * wy1);
}

__global__ __launch_bounds__(256) void texture_sample_u8(
        const f2v* __restrict__ x,
        const unsigned char* __restrict__ l1,
        const unsigned char* __restrict__ l2,
        const unsigned char* __restrict__ l3,
        const unsigned char* __restrict__ l4,
        const float2* __restrict__ sc,
        float* __restrict__ out, int n) {
    int i = blockIdx.x * blockDim.x + threadIdx.x;
    if (i >= n) return;
    float2 s1 = sc[0], s2 = sc[1], s3 = sc[2], s4 = sc[3];
    f2v g = __builtin_nontemporal_load(x + i);
    float gx = g.x * 2.0f - 1.0f;
    float gy = g.y * 2.0f - 1.0f;
    float acc;
    acc  = sample_layer_u8<4096, 4096>(l1, s1.x, s1.y, gx, gy);
    acc += sample_layer_u8<2048, 2048>(l2, s2.x, s2.y, gx, gy);
    acc += sample_layer_u8<1024, 1024>(l3, s3.x, s3.y, gx, gy);
    acc += sample_layer_u8< 512,  512>(l4, s4.x, s4.y, gx, gy);
    __builtin_nontemporal_store(acc, out + i);
}

// ---------- fallback: direct fp32 path (used only if ws too small) ----------
__device__ __forceinline__ float fetch_tap(const float* __restrict__ t, int W, int H, int x, int y) {
    bool valid = ((unsigned)x < (unsigned)W) & ((unsigned)y < (unsigned)H);
    int xc = min(max(x, 0), W - 1);
    int yc = min(max(y, 0), H - 1);
    float v = t[(size_t)yc * (size_t)W + (size_t)xc];
    return valid ? v : 0.0f;
}
__device__ __forceinline__ float sample_layer(const float* __restrict__ t, int W, int H,
                                              float gx, float gy) {
    float ix = ((gx + 1.0f) * (float)W - 1.0f) * 0.5f;
    float iy = ((gy + 1.0f) * (float)H - 1.0f) * 0.5f;
    float x0f = floorf(ix), y0f = floorf(iy);
    float wx1 = ix - x0f, wy1 = iy - y0f;
    float wx0 = 1.0f - wx1, wy0 = 1.0f - wy1;
    int x0 = (int)x0f, y0 = (int)y0f;
    float v00 = fetch_tap(t, W, H, x0,     y0);
    float v10 = fetch_tap(t, W, H, x0 + 1, y0);
    float v01 = fetch_tap(t, W, H, x0,     y0 + 1);
    float v11 = fetch_tap(t, W, H, x0 + 1, y0 + 1);
    return (v00 * wx0 + v10 * wx1) * wy0 + (v01 * wx0 + v11 * wx1) * wy1;
}
__global__ __launch_bounds__(256) void texture_sample_direct(
        const f2v* __restrict__ x,
        const float* __restrict__ l1, const float* __restrict__ l2,
        const float* __restrict__ l3, const float* __restrict__ l4,
        float* __restrict__ out, int n) {
    int i = blockIdx.x * blockDim.x + threadIdx.x;
    if (i >= n) return;
    f2v g = __builtin_nontemporal_load(x + i);
    float gx = g.x * 2.0f - 1.0f;
    float gy = g.y * 2.0f - 1.0f;
    float acc;
    acc  = sample_layer(l1, 4096, 4096, gx, gy);
    acc += sample_layer(l2, 2048, 2048, gx, gy);
    acc += sample_layer(l3, 1024, 1024, gx, gy);
    acc += sample_layer(l4,  512,  512, gx, gy);
    __builtin_nontemporal_store(acc, out + i);
}

extern "C" void kernel_launch(void* const* d_in, const int* in_sizes, int n_in,
                              void* d_out, int out_size, void* d_ws, size_t ws_size,
                              hipStream_t stream) {
    const f2v*   x  = (const f2v*)d_in[0];
    const float* l1 = (const float*)d_in[1];
    const float* l2 = (const float*)d_in[2];
    const float* l3 = (const float*)d_in[3];
    const float* l4 = (const float*)d_in[4];
    float* out = (float*)d_out;
    int n = out_size;                       // 4096*4096
    int block = 256;
    int grid = (n + block - 1) / block;

    // ws layout: t1 16MB | t2 4MB | t3 1MB | t4 0.25MB | mm 32B | sc 32B
    const size_t OFF1 = 0;
    const size_t OFF2 = (size_t)4096 * 4096;
    const size_t OFF3 = OFF2 + (size_t)2048 * 2048;
    const size_t OFF4 = OFF3 + (size_t)1024 * 1024;
    const size_t OFFM = OFF4 + (size_t)512 * 512;
    const size_t OFFS = OFFM + 8 * sizeof(unsigned);
    const size_t NEED = OFFS + 4 * sizeof(float2);

    if (ws_size >= NEED) {
        unsigned char* t1 = (unsigned char*)d_ws + OFF1;
        unsigned char* t2 = (unsigned char*)d_ws + OFF2;
        unsigned char* t3 = (unsigned char*)d_ws + OFF3;
        unsigned char* t4 = (unsigned char*)d_ws + OFF4;
        unsigned* mm = (unsigned*)((char*)d_ws + OFFM);
        float2*   sc = (float2*)((char*)d_ws + OFFS);

        init_mm<<<1, 64, 0, stream>>>(mm);
        minmax_kernel<<<2048, 256, 0, stream>>>((const float4*)l1, 4096 * 4096 / 4, mm + 0);
        minmax_kernel<<<1024, 256, 0, stream>>>((const float4*)l2, 2048 * 2048 / 4, mm + 2);
        minmax_kernel<<< 512, 256, 0, stream>>>((const float4*)l3, 1024 * 1024 / 4, mm + 4);
        minmax_kernel<<< 256, 256, 0, stream>>>((const float4*)l4,  512 *  512 / 4, mm + 6);
        finalize_sc<<<1, 64, 0, stream>>>(mm, sc);

        int nt1 = (4096 / 8) * (4096 / 8), nt2 = (2048 / 8) * (2048 / 8);
        int nt3 = (1024 / 8) * (1024 / 8), nt4 = (512 / 8) * (512 / 8);
        convert_tiled_u8<<<(nt1 + 255) / 256, 256, 0, stream>>>(l1, t1, 4096, 9, nt1, sc, 0);
        convert_tiled_u8<<<(nt2 + 255) / 256, 256, 0, stream>>>(l2, t2, 2048, 8, nt2, sc, 1);
        convert_tiled_u8<<<(nt3 + 255) / 256, 256, 0, stream>>>(l3, t3, 1024, 7, nt3, sc, 2);
        convert_tiled_u8<<<(nt4 + 255) / 256, 256, 0, stream>>>(l4, t4,  512, 6, nt4, sc, 3);

        texture_sample_u8<<<grid, block, 0, stream>>>(x, t1, t2, t3, t4, sc, out, n);
    } else {
        texture_sample_direct<<<grid, block, 0, stream>>>(x, l1, l2, l3, l4, out, n);
    }
}